// Round 6
// baseline (16275.803 us; speedup 1.0000x reference)
//
#include <hip/hip_runtime.h>
#include <stdint.h>
#include <math.h>

// plmDCA one Gibbs sweep — bitwise-faithful replay of the JAX reference.
// Confirmed (r1, absmax 0.0): partitionable threefry (o0^o1), Eigen KC=288
// k-blocked left-fold sum order, f64-computed f32-rounded logs.
// r2: desynced small blocks thrash L3 -> keep 256 blocks / 1 per CU.
// r3 (best, 5.9ms): global divergent gather; FETCH 962MB = 8 XCD x row x 256
//     steps exactly; floor = L1 miss/fill serialization on divergent gathers.
// r4: lambda-captured float4 r[6] -> address-taken -> SCRATCH (45GB writes).
// r5: global_load_lds streams bypassed L2/L3 (hbm_bytes ~= staged volume,
//     2.2TB/s sustained) -> DMA unusable for many-CUs-same-row staging.
// r6: wave-private LDS double-buffer staged via CACHED float4 loads +
//     immediate ds_write_b128; named vars only; gather from LDS (DS pipe).

#define NSEQ 8192
#define LRES 256
#define QST  21
#define SPB  32                // sequences per block
#define NTHREADS (SPB * QST)   // 672
#define NWAVES 11              // wave 10 has 32 lanes (a=20 only)
#define CH   32                // l per chunk
#define NCH  (LRES / CH)       // 8 chunks per step
#define STRIDEW 688            // LDS words per a-strip (672 + 16 pad)
#define BUFW (2 * STRIDEW)     // 1376 words per buffer (2 strips)
#define WAVEW (2 * BUFW)       // 2752 words per wave (double buffer)
#define CHU  168               // float4 units per (strip, chunk)
#define SEGU 1344              // float4 units per strip per row
#define ROWU 28224             // float4 units per J row

// Per-l KC-crossing table: 255 = plain add; else threshold on b for boundary m.
struct KcTbl {
  unsigned char thr[LRES];
  constexpr KcTbl() : thr() {
    for (int i = 0; i < LRES; ++i) thr[i] = 255;
    for (int m = 1; m < 19; ++m) {
      int l = (288 * m) / 21;
      thr[l] = (unsigned char)(288 * m - 21 * l);
    }
  }
};
static constexpr KcTbl KC_TBL{};

__device__ __forceinline__ uint32_t rotl32(uint32_t v, uint32_t r) {
  return (v << r) | (v >> (32u - r));
}

// JAX/Random123 Threefry-2x32, 20 rounds.
__device__ __forceinline__ void threefry2x32(uint32_t k0, uint32_t k1,
                                             uint32_t c0, uint32_t c1,
                                             uint32_t& o0, uint32_t& o1) {
  uint32_t ks2 = k0 ^ k1 ^ 0x1BD11BDAu;
  uint32_t x0 = c0 + k0;
  uint32_t x1 = c1 + k1;
#define TF_ROUND(r) { x0 += x1; x1 = rotl32(x1, r); x1 ^= x0; }
  TF_ROUND(13u) TF_ROUND(15u) TF_ROUND(26u) TF_ROUND(6u)
  x0 += k1;  x1 += ks2 + 1u;
  TF_ROUND(17u) TF_ROUND(29u) TF_ROUND(16u) TF_ROUND(24u)
  x0 += ks2; x1 += k0 + 2u;
  TF_ROUND(13u) TF_ROUND(15u) TF_ROUND(26u) TF_ROUND(6u)
  x0 += k0;  x1 += k1 + 3u;
  TF_ROUND(17u) TF_ROUND(29u) TF_ROUND(16u) TF_ROUND(24u)
  x0 += k1;  x1 += ks2 + 4u;
  TF_ROUND(13u) TF_ROUND(15u) TF_ROUND(26u) TF_ROUND(6u)
  x0 += ks2; x1 += k0 + 5u;
#undef TF_ROUND
  o0 = x0; o1 = x1;
}

// JAX gumbel: -log(-log(uniform(tiny,1))), logs f64-computed f32-rounded.
__device__ __forceinline__ float gumbel_f32(uint32_t bits) {
  float f = __uint_as_float((bits >> 9) | 0x3f800000u) - 1.0f;
  float u = fmaxf(1.17549435e-38f, f + 1.17549435e-38f);
  float w = (float)log((double)u);
  float t = -w;
  float g = -(float)log((double)t);
  return g;
}

__global__ __launch_bounds__(NTHREADS, 1)
void gibbs_sweep(const float* __restrict__ X, const int* __restrict__ order,
                 const float* __restrict__ h, const float* __restrict__ J,
                 const float* __restrict__ betaPtr, float* __restrict__ out) {
  __shared__ __align__(16) float jbuf[NWAVES * WAVEW];  // 121088 B wave-private
  __shared__ uint32_t sbst[(LRES / 4) * SPB];           // packed states (8 KB)
  __shared__ float    vals[QST][SPB];
  __shared__ uint32_t tk0[LRES], tk1[LRES];             // per-step threefry keys
  __shared__ int      sord[LRES];

  const int nl   = threadIdx.x;      // 0..31 local sequence
  const int a    = threadIdx.y;      // 0..20 category
  const int tid  = nl + SPB * a;     // 0..671
  const int lane = tid & 63;
  const int wv   = tid >> 6;         // wave id 0..10
  const int n0   = blockIdx.x * SPB;
  const int n    = n0 + nl;
  const float beta = betaPtr[0];

  // ---- init: keys, order cache ----
  for (int t = tid; t < LRES; t += NTHREADS) {
    uint32_t o0, o1;
    threefry2x32(0u, 42u, 0u, (uint32_t)t, o0, o1);
    tk0[t] = o0; tk1[t] = o1;
    sord[t] = order[t];
  }

  // ---- init packed state from one-hot X ----
  for (int idx = tid; idx < (LRES / 4) * SPB; idx += NTHREADS) {
    int s  = idx & (SPB - 1);
    int wg = idx / SPB;
    uint32_t w = 0;
#pragma unroll
    for (int j = 0; j < 4; ++j) {
      int l = 4 * wg + j;
      const float* xp = X + ((size_t)(n0 + s) * LRES + l) * QST;
      int b = 0;
#pragma unroll
      for (int q = 0; q < QST; ++q) b = (xp[q] > 0.5f) ? q : b;
      w |= ((uint32_t)b) << (8 * j);
    }
    sbst[wg * SPB + s] = w;
  }
  __syncthreads();

  // ---- per-thread staging offsets (computed once; straight-line, no arrays)
  const float4* Jv = (const float4*)J;
  const int nact = (wv == NWAVES - 1) ? 32 : 64;   // active lanes this wave
  const int nseg = (wv == NWAVES - 1) ? 1 : 2;     // a-strips this wave stages
  float* jw = jbuf + wv * WAVEW;                   // this wave's LDS region

  const int u0 = lane,            s0 = u0 / CHU, w0 = u0 - s0 * CHU;
  const int u1 = lane + nact,     s1 = u1 / CHU, w1 = u1 - s1 * CHU;
  const int u2 = lane + 2 * nact, s2 = u2 / CHU, w2 = u2 - s2 * CHU;
  const int u3 = lane + 3 * nact, s3 = u3 / CHU, w3 = u3 - s3 * CHU;
  const int u4 = lane + 4 * nact, s4 = u4 / CHU, w4 = u4 - s4 * CHU;
  const int u5 = lane + 5 * nact, s5 = u5 / CHU, w5 = u5 - s5 * CHU;
  const bool val5 = u5 < nseg * CHU;               // only k=5 can be inactive
  const int gk0 = (2 * wv + s0) * SEGU + w0, ow0 = s0 * STRIDEW + 4 * w0;
  const int gk1 = (2 * wv + s1) * SEGU + w1, ow1 = s1 * STRIDEW + 4 * w1;
  const int gk2 = (2 * wv + s2) * SEGU + w2, ow2 = s2 * STRIDEW + 4 * w2;
  const int gk3 = (2 * wv + s3) * SEGU + w3, ow3 = s3 * STRIDEW + 4 * w3;
  const int gk4 = (2 * wv + s4) * SEGU + w4, ow4 = s4 * STRIDEW + 4 * w4;
  const int gk5 = (2 * wv + s5) * SEGU + w5, ow5 = s5 * STRIDEW + 4 * w5;

  // per-thread gather base (own a-strip), buffer 0
  const float* gb0 = jw + (a & 1) * STRIDEW;

  // ---- prologue: stage chunk 0 of step 0 into buffer 0 (wave-local) ----
  {
    const float4* cb = Jv + (size_t)sord[0] * ROWU;
    float4 v0 = cb[gk0], v1 = cb[gk1], v2 = cb[gk2],
           v3 = cb[gk3], v4 = cb[gk4], v5;
    if (val5) v5 = cb[gk5];
    *(float4*)(jw + ow0) = v0; *(float4*)(jw + ow1) = v1;
    *(float4*)(jw + ow2) = v2; *(float4*)(jw + ow3) = v3;
    *(float4*)(jw + ow4) = v4;
    if (val5) *(float4*)(jw + ow5) = v5;
  }

  // ---- sequential Gibbs sweep ----
  for (int t = 0; t < LRES; ++t) {
    const int i = sord[t];

    float tot = 0.0f, part = 0.0f;
#pragma unroll
    for (int c = 0; c < NCH; ++c) {
      __builtin_amdgcn_sched_barrier(0);   // pin per-chunk region (VGPR cap)
      // 1. issue next chunk's cached loads (next step's chunk 0 at c==7)
      const int nrow = (c < NCH - 1) ? i : sord[(t + 1) & (LRES - 1)];
      const int nc   = (c < NCH - 1) ? c + 1 : 0;
      const float4* cb = Jv + (size_t)nrow * ROWU + (size_t)(nc * CHU);
      float4 v0 = cb[gk0], v1 = cb[gk1], v2 = cb[gk2],
             v3 = cb[gk3], v4 = cb[gk4], v5;
      if (val5) v5 = cb[gk5];

      // 2. gather current chunk from LDS (Eigen KC=288 left-fold order)
      const float* gb = gb0 + (c & 1) * BUFW;
#pragma unroll
      for (int lg = 0; lg < CH / 4; ++lg) {
        uint32_t w = sbst[(c * (CH / 4) + lg) * SPB + nl];
#pragma unroll
        for (int j = 0; j < 4; ++j) {
          const int l = c * CH + 4 * lg + j;   // compile-time after unroll
          uint32_t b = (w >> (8 * j)) & 0xffu;
          float jv = gb[(4 * lg + j) * QST + b];
          const int thr = KC_TBL.thr[l];       // folds at compile time
          if (thr == 255) {
            part += jv;
          } else if (thr == 0) {
            tot += part; part = jv;
          } else {
            if ((int)b >= thr) { tot += part; part = jv; }
            else               { part += jv; tot += part; part = 0.0f; }
          }
        }
      }

      // 3. write staged regs to the other buffer (wave-local, no barrier)
      float* wb = jw + ((c + 1) & 1) * BUFW;
      *(float4*)(wb + ow0) = v0; *(float4*)(wb + ow1) = v1;
      *(float4*)(wb + ow2) = v2; *(float4*)(wb + ow3) = v3;
      *(float4*)(wb + ow4) = v4;
      if (val5) *(float4*)(wb + ow5) = v5;
    }
    tot += part;

    float lo = h[i * QST + a] + tot;

    uint32_t o0, o1;
    threefry2x32(tk0[t], tk1[t], 0u, (uint32_t)(n * QST + a), o0, o1);
    float g = gumbel_f32(o0 ^ o1);

    vals[a][nl] = g + beta * lo;
    __syncthreads();

    if (a == 0) {                               // first-max argmax over 21
      float best = vals[0][nl];
      int bi = 0;
#pragma unroll
      for (int q = 1; q < QST; ++q) {
        float vv = vals[q][nl];
        if (vv > best) { best = vv; bi = q; }
      }
      unsigned char* bp = reinterpret_cast<unsigned char*>(sbst);
      bp[((i >> 2) * SPB + nl) * 4 + (i & 3)] = (unsigned char)bi;
    }
    __syncthreads();
  }

  // ---- expand packed state to one-hot f32 output ----
  const size_t base = (size_t)n0 * LRES * QST;
  for (int idx = tid; idx < SPB * LRES * QST; idx += NTHREADS) {
    int s   = idx / (LRES * QST);
    int rem = idx - s * (LRES * QST);
    int l   = rem / QST;
    int q   = rem - l * QST;
    uint32_t w = sbst[(l >> 2) * SPB + s];
    int b = (int)((w >> (8 * (l & 3))) & 0xffu);
    out[base + idx] = (b == q) ? 1.0f : 0.0f;
  }
}

extern "C" void kernel_launch(void* const* d_in, const int* in_sizes, int n_in,
                              void* d_out, int out_size, void* d_ws, size_t ws_size,
                              hipStream_t stream) {
  const float* X     = (const float*)d_in[0];
  const int*   order = (const int*)  d_in[1];
  const float* h     = (const float*)d_in[2];
  const float* J     = (const float*)d_in[3];
  const float* beta  = (const float*)d_in[4];
  float* out = (float*)d_out;

  dim3 grid(NSEQ / SPB);      // 256 blocks, 1 per CU
  dim3 block(SPB, QST);       // 32 x 21 = 672 threads
  hipLaunchKernelGGL(gibbs_sweep, grid, block, 0, stream, X, order, h, J, beta, out);
}